// Round 1
// baseline (414.621 us; speedup 1.0000x reference)
//
#include <hip/hip_runtime.h>

#define KOFF 9
#define N_PTS 262144
#define D 32
#define PPB 8          // pairs per block
#define THREADS 256

// out[n][d] = bias[d], vectorized float4 (8 float4 per row)
__global__ void bias_init_kernel(const float* __restrict__ bias,
                                 float* __restrict__ out) {
    int i = blockIdx.x * blockDim.x + threadIdx.x;   // one float4 per thread
    float4 b = ((const float4*)bias)[i & 7];
    ((float4*)out)[i] = b;
}

__global__ void __launch_bounds__(THREADS)
scatter_conv_kernel(const float* __restrict__ feat,
                    const float* __restrict__ weight,
                    const int* __restrict__ indice_pairs,
                    const int* __restrict__ indice_pair_num,
                    float* __restrict__ out) {
    const int k   = blockIdx.y;
    const int n_k = indice_pair_num[k];
    const int p0  = blockIdx.x * PPB;
    if (p0 >= n_k) return;                 // whole block out of range

    __shared__ float w[D][D];              // w[c][d] = weight[d][k][c]
    __shared__ float f[PPB][D];

    for (int idx = threadIdx.x; idx < D * D; idx += THREADS) {
        int c = idx >> 5, d = idx & 31;
        w[c][d] = weight[d * (KOFF * D) + k * D + c];
    }

    const int pp = threadIdx.x >> 5;       // pair within block, 0..7
    const int d  = threadIdx.x & 31;       // output channel
    const int p  = p0 + pp;
    const int* in_idx  = indice_pairs + (size_t)k * N_PTS;
    const int* out_idx = indice_pairs + (size_t)(KOFF + k) * N_PTS;

    int orow = -1;
    if (p < n_k) {
        int irow = in_idx[p];
        orow     = out_idx[p];
        f[pp][d] = feat[(size_t)irow * D + d];   // coalesced 128B per pair
    }
    __syncthreads();

    if (p < n_k) {
        float acc = 0.f;
#pragma unroll
        for (int c = 0; c < D; ++c)
            acc += f[pp][c] * w[c][d];           // f: LDS broadcast, w: conflict-free
        atomicAdd(&out[(size_t)orow * D + d], acc);
    }
}

extern "C" void kernel_launch(void* const* d_in, const int* in_sizes, int n_in,
                              void* d_out, int out_size, void* d_ws, size_t ws_size,
                              hipStream_t stream) {
    const float* feat            = (const float*)d_in[0];
    const float* weight          = (const float*)d_in[1];
    const float* bias            = (const float*)d_in[2];
    const int*   indice_pairs    = (const int*)d_in[3];
    const int*   indice_pair_num = (const int*)d_in[4];
    float*       out             = (float*)d_out;

    int n_vec4 = N_PTS * D / 4;                       // 2M float4
    bias_init_kernel<<<n_vec4 / 256, 256, 0, stream>>>(bias, out);

    dim3 grid((N_PTS + PPB - 1) / PPB, KOFF);
    scatter_conv_kernel<<<grid, THREADS, 0, stream>>>(
        feat, weight, indice_pairs, indice_pair_num, out);
}